// Round 1
// baseline (103392.542 us; speedup 1.0000x reference)
//
#include <hip/hip_runtime.h>
#include <hip/hip_bf16.h>
#include <math.h>

// Problem constants
#define T_ 256
#define B_ 128
#define VOC_ 256
#define IN_DIM_ 258
#define EMB_ 512
#define N_ 1024
#define H_ 2048
#define WIN_ 32
#define OUT_EMB_ 1024

__device__ __forceinline__ float sigmoidf_(float x) { return 1.f / (1.f + expf(-x)); }

// ---------------------------------------------------------------------------
// Generic fp32 split-K GEMM.
//   A = concat([A0(k0), A1(k1), A2(k2)]) along K (row-major, per-segment lda)
//   W is (Ktot x N) row-major.
// If bias != nullptr (requires gridDim.z==1): C[M x N] = A@W + bias (final).
// Else: C is partials laid out [gridDim.z][M][N]; consumer sums over z.
// Block: 256 threads, 64x64 output tile, 4x4 per-thread register tile, BK=16.
// Segment boundaries and kchunk are multiples of 16 for all call sites, so a
// 16-wide K-tile never straddles a segment boundary (except the guarded
// ragged tail at kend, used only by the emb GEMM with K=258).
// ---------------------------------------------------------------------------
__global__ __launch_bounds__(256)
void gemm_f32(const float* __restrict__ A0, int k0, int lda0,
              const float* __restrict__ A1, int k1, int lda1,
              const float* __restrict__ A2, int k2, int lda2,
              const float* __restrict__ W, int N,
              float* __restrict__ C, const float* __restrict__ bias,
              int M, int Ktot, int kchunk)
{
    __shared__ float As[16][68];   // +4 pad: keeps 16B alignment, kills store conflicts
    __shared__ float Ws[16][64];

    const int tid = threadIdx.x;
    const int bn = blockIdx.x, bm = blockIdx.y, bz = blockIdx.z;
    const int kbeg = bz * kchunk;
    const int kend = min(kbeg + kchunk, Ktot);
    const int tc = tid & 15, tr = tid >> 4;

    float acc[4][4] = {{0.f, 0.f, 0.f, 0.f}, {0.f, 0.f, 0.f, 0.f},
                       {0.f, 0.f, 0.f, 0.f}, {0.f, 0.f, 0.f, 0.f}};

    for (int kb = kbeg; kb < kend; kb += 16) {
        // segment select (whole tile lives in one segment by construction)
        const float* Aseg; int soff, slda;
        if (kb < k0)           { Aseg = A0; soff = 0;       slda = lda0; }
        else if (kb < k0 + k1) { Aseg = A1; soff = k0;      slda = lda1; }
        else                   { Aseg = A2; soff = k0 + k1; slda = lda2; }

        // load A tile: 64 rows x 16 k, stored transposed As[k][row]
        #pragma unroll
        for (int l = 0; l < 4; ++l) {
            int i = tid + l * 256;
            int r = i >> 4, kk = i & 15;
            int kg = kb + kk;
            As[kk][r] = (kg < kend)
                ? Aseg[(size_t)(bm * 64 + r) * slda + (kg - soff)] : 0.f;
        }
        // load W tile: 16 k x 64 cols
        #pragma unroll
        for (int l = 0; l < 4; ++l) {
            int i = tid + l * 256;
            int kk = i >> 6, cc = i & 63;
            int kg = kb + kk;
            Ws[kk][cc] = (kg < kend) ? W[(size_t)kg * N + bn * 64 + cc] : 0.f;
        }
        __syncthreads();

        #pragma unroll
        for (int kk = 0; kk < 16; ++kk) {
            const float4 av = *reinterpret_cast<const float4*>(&As[kk][tr * 4]);
            const float4 wv = *reinterpret_cast<const float4*>(&Ws[kk][tc * 4]);
            acc[0][0] += av.x * wv.x; acc[0][1] += av.x * wv.y;
            acc[0][2] += av.x * wv.z; acc[0][3] += av.x * wv.w;
            acc[1][0] += av.y * wv.x; acc[1][1] += av.y * wv.y;
            acc[1][2] += av.y * wv.z; acc[1][3] += av.y * wv.w;
            acc[2][0] += av.z * wv.x; acc[2][1] += av.z * wv.y;
            acc[2][2] += av.z * wv.z; acc[2][3] += av.z * wv.w;
            acc[3][0] += av.w * wv.x; acc[3][1] += av.w * wv.y;
            acc[3][2] += av.w * wv.z; acc[3][3] += av.w * wv.w;
        }
        __syncthreads();
    }

    if (bias) {
        #pragma unroll
        for (int i = 0; i < 4; ++i) {
            int r = bm * 64 + tr * 4 + i;
            int c0c = bn * 64 + tc * 4;
            float4 v;
            v.x = acc[i][0] + bias[c0c + 0];
            v.y = acc[i][1] + bias[c0c + 1];
            v.z = acc[i][2] + bias[c0c + 2];
            v.w = acc[i][3] + bias[c0c + 3];
            *reinterpret_cast<float4*>(&C[(size_t)r * N + c0c]) = v;
        }
    } else {
        float* Cp = C + (size_t)bz * (size_t)M * (size_t)N;
        #pragma unroll
        for (int i = 0; i < 4; ++i) {
            int r = bm * 64 + tr * 4 + i;
            int c0c = bn * 64 + tc * 4;
            float4 v;
            v.x = acc[i][0]; v.y = acc[i][1]; v.z = acc[i][2]; v.w = acc[i][3];
            *reinterpret_cast<float4*>(&Cp[(size_t)r * N + c0c]) = v;
        }
    }
}

// ---------------------------------------------------------------------------
// LSTM pointwise: sums ks split-K partials of z (B x 4N), adds bias, applies
// gates, updates h/c in place. If bufslot != nullptr (layer 1), also writes
// hs = [h0, h1] into the attention ring-buffer slot.
// ---------------------------------------------------------------------------
__global__ __launch_bounds__(256)
void lstm_pw(const float* __restrict__ zp, int ks, const float* __restrict__ bias,
             float* __restrict__ h, float* __restrict__ c,
             float* __restrict__ bufslot, const float* __restrict__ hother)
{
    int idx = blockIdx.x * 256 + threadIdx.x;   // < B_*N_ = 131072
    int b = idx >> 10, j = idx & 1023;
    float zf = bias[j], zi = bias[1024 + j], zo = bias[2048 + j], zm = bias[3072 + j];
    const float* p = zp + (size_t)b * 4096;
    for (int s = 0; s < ks; ++s, p += (size_t)B_ * 4096) {
        zf += p[j]; zi += p[1024 + j]; zo += p[2048 + j]; zm += p[3072 + j];
    }
    float f = sigmoidf_(zf), ii = sigmoidf_(zi), o = sigmoidf_(zo);
    float m = tanhf(zm);
    float cn = c[idx] * f + m * ii;
    float hn = tanhf(cn) * o;
    c[idx] = cn;
    h[idx] = hn;
    if (bufslot) {
        bufslot[b * 2048 + 1024 + j] = hn;          // h1 half
        bufslot[b * 2048 + j] = hother[idx];        // h0 half
    }
}

// ---------------------------------------------------------------------------
// Attention: one block per batch element. scores = softmax(buf . hs),
// from_att = sum_w p_w * buf[w]. Ring order is irrelevant (softmax weighted
// sum is permutation invariant); zero slots match the reference's zero rows.
// ---------------------------------------------------------------------------
__global__ __launch_bounds__(256)
void attn_kernel(const float* __restrict__ h0, const float* __restrict__ h1,
                 const float* __restrict__ buf, float* __restrict__ fa)
{
    const int b = blockIdx.x;
    __shared__ float hsl[2048];
    __shared__ float pl[32];
    const int tid = threadIdx.x;

    for (int i = tid; i < 1024; i += 256) {
        hsl[i] = h0[b * 1024 + i];
        hsl[1024 + i] = h1[b * 1024 + i];
    }
    __syncthreads();

    const int wv = tid >> 6, lane = tid & 63;
    for (int w = wv; w < 32; w += 4) {
        const float* br = buf + ((size_t)w * B_ + b) * 2048;
        float s = 0.f;
        for (int hh = lane; hh < 2048; hh += 64) s += br[hh] * hsl[hh];
        #pragma unroll
        for (int off = 32; off > 0; off >>= 1) s += __shfl_down(s, off);
        if (lane == 0) pl[w] = s;
    }
    __syncthreads();

    if (tid < 64) {
        float v = (lane < 32) ? pl[lane] : -3.4e38f;
        float m = v;
        #pragma unroll
        for (int off = 32; off > 0; off >>= 1) m = fmaxf(m, __shfl_xor(m, off));
        float e = (lane < 32) ? expf(v - m) : 0.f;
        float ssum = e;
        #pragma unroll
        for (int off = 32; off > 0; off >>= 1) ssum += __shfl_xor(ssum, off);
        if (lane < 32) pl[lane] = e / ssum;
    }
    __syncthreads();

    for (int hh = tid; hh < 2048; hh += 256) {
        float a = 0.f;
        #pragma unroll
        for (int w = 0; w < 32; ++w) a += pl[w] * buf[((size_t)w * B_ + b) * 2048 + hh];
        fa[b * 2048 + hh] = a;
    }
}

// gated = sigmoid(sum Gp) * hs
__global__ __launch_bounds__(256)
void gate_epi(const float* __restrict__ Gp, int ks,
              const float* __restrict__ h0, const float* __restrict__ h1,
              float* __restrict__ gated)
{
    int idx = blockIdx.x * 256 + threadIdx.x;   // < B_*H_ = 262144
    int b = idx >> 11, j = idx & 2047;
    float g = 0.f;
    const float* p = Gp + (size_t)b * 2048 + j;
    for (int s = 0; s < ks; ++s, p += (size_t)B_ * 2048) g += *p;
    float hs = (j < 1024) ? h0[b * 1024 + j] : h1[b * 1024 + (j - 1024)];
    gated[idx] = hs * sigmoidf_(g);
}

// R = relu(sum Rp + be)
__global__ __launch_bounds__(256)
void relu_epi(const float* __restrict__ Rp, int ks, const float* __restrict__ be,
              float* __restrict__ Rb)
{
    int idx = blockIdx.x * 256 + threadIdx.x;   // < B_*OUT_EMB_ = 131072
    int b = idx >> 10, j = idx & 1023;
    float r = be[j];
    const float* p = Rp + (size_t)b * 1024 + j;
    for (int s = 0; s < ks; ++s, p += (size_t)B_ * 1024) r += *p;
    Rb[idx] = fmaxf(r, 0.f);
}

// out = sum Lp + bo
__global__ __launch_bounds__(256)
void out_epi(const float* __restrict__ Lp, int ks, const float* __restrict__ bo,
             float* __restrict__ outp)
{
    int idx = blockIdx.x * 256 + threadIdx.x;   // < B_*VOC_ = 32768
    int j = idx & 255;
    float v = bo[j];
    const float* p = Lp + idx;
    for (int s = 0; s < ks; ++s, p += (size_t)B_ * 256) v += *p;
    outp[idx] = v;
}

// ---------------------------------------------------------------------------
extern "C" void kernel_launch(void* const* d_in, const int* in_sizes, int n_in,
                              void* d_out, int out_size, void* d_ws, size_t ws_size,
                              hipStream_t stream)
{
    const float* inp  = (const float*)d_in[0];
    const float* embW = (const float*)d_in[1];
    const float* embB = (const float*)d_in[2];
    const float* M0   = (const float*)d_in[3];
    const float* B0   = (const float*)d_in[4];
    const float* M1   = (const float*)d_in[5];
    const float* B1   = (const float*)d_in[6];
    const float* Wg   = (const float*)d_in[7];
    const float* We   = (const float*)d_in[8];
    const float* be   = (const float*)d_in[9];
    const float* Wo   = (const float*)d_in[10];
    const float* bo   = (const float*)d_in[11];
    float* out = (float*)d_out;

    // workspace layout (floats)
    float* ws   = (float*)d_ws;
    float* E    = ws;                         // T*B*EMB          = 16777216
    float* h0   = E    + (size_t)16777216;    // B*N              = 131072
    float* c0   = h0   + 131072;
    float* h1   = c0   + 131072;
    float* c1   = h1   + 131072;
    float* fa   = c1   + 131072;              // B*H              = 262144
    float* buf  = fa   + 262144;              // WIN*B*H          = 8388608
    float* z0p  = buf  + 8388608;             // 4 * B*4N         = 2097152
    float* z1p  = z0p  + 2097152;             // 4 * B*4N         = 2097152
    float* Gp   = z1p  + 2097152;             // 8 * B*H          = 2097152
    float* Rp   = Gp   + 2097152;             // 16 * B*OUT_EMB   = 2097152
    float* Lp   = Rp   + 2097152;             // 32 * B*VOC       = 1048576
    float* gated= Lp   + 1048576;             // B*H              = 262144
    float* Rb   = gated+ 262144;              // B*OUT_EMB        = 131072
    const size_t need_floats = 16777216 + 4 * 131072 + 262144 + 8388608
                             + 4 * 2097152 + 1048576 + 262144 + 131072;
    if (ws_size < need_floats * sizeof(float)) return;  // ws too small — bail

    // zero the recurrent state + ring buffer (harness does not re-poison)
    hipMemsetAsync(h0, 0, (size_t)(4 * 131072 + 262144 + 8388608) * sizeof(float), stream);

    // E = inp @ embW + embB   (M = T*B = 32768, N = 512, K = 258)
    gemm_f32<<<dim3(8, 512, 1), 256, 0, stream>>>(
        inp, 258, 258, nullptr, 0, 0, nullptr, 0, 0,
        embW, 512, E, embB, 32768, 258, 258);

    for (int t = 0; t < T_; ++t) {
        const float* Et = E + (size_t)t * B_ * EMB_;
        float* bufslot = buf + (size_t)(t & 31) * B_ * H_;

        // z0 = [E_t, from_att, h0] @ M0 (K=3584), split-K=4
        gemm_f32<<<dim3(64, 2, 4), 256, 0, stream>>>(
            Et, 512, 512, fa, 2048, 2048, h0, 1024, 1024,
            M0, 4096, z0p, nullptr, 128, 3584, 896);
        lstm_pw<<<512, 256, 0, stream>>>(z0p, 4, B0, h0, c0, nullptr, nullptr);

        // z1 = [h0, h1] @ M1 (K=2048), split-K=4
        gemm_f32<<<dim3(64, 2, 4), 256, 0, stream>>>(
            h0, 1024, 1024, h1, 1024, 1024, nullptr, 0, 0,
            M1, 4096, z1p, nullptr, 128, 2048, 512);
        lstm_pw<<<512, 256, 0, stream>>>(z1p, 4, B1, h1, c1, bufslot, h0);

        // attention (updates from_att for next step)
        attn_kernel<<<128, 256, 0, stream>>>(h0, h1, buf, fa);

        // head: G = hs @ Wg (split-K=8) -> gated = sigmoid(G)*hs
        gemm_f32<<<dim3(32, 2, 8), 256, 0, stream>>>(
            h0, 1024, 1024, h1, 1024, 1024, nullptr, 0, 0,
            Wg, 2048, Gp, nullptr, 128, 2048, 256);
        gate_epi<<<1024, 256, 0, stream>>>(Gp, 8, h0, h1, gated);

        // R = relu(gated @ We + be) (split-K=16)
        gemm_f32<<<dim3(16, 2, 16), 256, 0, stream>>>(
            gated, 2048, 2048, nullptr, 0, 0, nullptr, 0, 0,
            We, 1024, Rp, nullptr, 128, 2048, 128);
        relu_epi<<<512, 256, 0, stream>>>(Rp, 16, be, Rb);

        // logits = R @ Wo + bo (split-K=32)
        gemm_f32<<<dim3(4, 2, 32), 256, 0, stream>>>(
            Rb, 1024, 1024, nullptr, 0, 0, nullptr, 0, 0,
            Wo, 256, Lp, nullptr, 128, 1024, 32);
        out_epi<<<128, 256, 0, stream>>>(Lp, 32, bo, out + (size_t)t * B_ * VOC_);
    }
}

// Round 3
// 40533.350 us; speedup vs baseline: 2.5508x; 2.5508x over previous
//
#include <hip/hip_runtime.h>
#include <hip/hip_bf16.h>
#include <math.h>

#define T_ 256
#define B_ 128
#define VOC_ 256
#define EMB_ 512
#define N_ 1024
#define H_ 2048
#define WIN_ 32
#define OUT_EMB_ 1024

typedef _Float16 half8 __attribute__((ext_vector_type(8)));
typedef float f32x4 __attribute__((ext_vector_type(4)));

__device__ __forceinline__ float sigmoidf_(float x) { return 1.f / (1.f + expf(-x)); }

// ---------------------------------------------------------------------------
// fp16 MFMA GEMM.  C[M x N] = concat_K(A0,A1,A2) @ BT^T  (BT is [N][ldb] fp16,
// i.e. W transposed, k-contiguous).  All K and segment boundaries %32 == 0.
// Block: 256 thr = 4 waves (2x2), tile 64x64, wave 32x32, mfma 16x16x32.
// mode 0: partial fp32 slab at Cf + bz*M*N           (split-K, gridDim.z>1)
// mode 1: Cf = acc + bias (bias may be null)          (final fp32)
// mode 2: Ch = (f16)max(acc + bias, 0)                (final fp16, relu)
// mode 3: Ch = (f16)(acc + bias)                      (final fp16)
// ---------------------------------------------------------------------------
__global__ __launch_bounds__(256)
void gemm_h(const _Float16* __restrict__ A0, int k0, int lda0,
            const _Float16* __restrict__ A1, int k1, int lda1,
            const _Float16* __restrict__ A2, int k2, int lda2,
            const _Float16* __restrict__ BT, int ldb,
            int N, int Ktot, int kchunk, int M,
            float* __restrict__ Cf, _Float16* __restrict__ Ch,
            const float* __restrict__ bias, int mode)
{
    __shared__ _Float16 As[64][40];   // +8 pad (16B) keeps alignment, spreads banks
    __shared__ _Float16 Bs[64][40];

    const int tid = threadIdx.x;
    const int bn = blockIdx.x, bm = blockIdx.y, bz = blockIdx.z;
    const int kbeg = bz * kchunk;
    const int kend = min(kbeg + kchunk, Ktot);
    const int lane = tid & 63, wid = tid >> 6;
    const int wm = wid >> 1, wn = wid & 1;
    const int l15 = lane & 15, l4 = lane >> 4;
    const int ar = tid >> 2, ak = (tid & 3) * 8;   // staging: row, k-offset

    f32x4 acc[2][2];
    #pragma unroll
    for (int i = 0; i < 2; ++i)
        #pragma unroll
        for (int j = 0; j < 2; ++j) acc[i][j] = (f32x4){0.f, 0.f, 0.f, 0.f};

    for (int kb = kbeg; kb < kend; kb += 32) {
        const _Float16* Ag; int so, ld;
        if (kb < k0)           { Ag = A0; so = 0;       ld = lda0; }
        else if (kb < k0 + k1) { Ag = A1; so = k0;      ld = lda1; }
        else                   { Ag = A2; so = k0 + k1; ld = lda2; }

        *(half8*)&As[ar][ak] =
            *(const half8*)(Ag + (size_t)(bm * 64 + ar) * ld + (kb - so + ak));
        *(half8*)&Bs[ar][ak] =
            *(const half8*)(BT + (size_t)(bn * 64 + ar) * ldb + (kb + ak));
        __syncthreads();

        half8 a0 = *(half8*)&As[wm * 32 + l15][l4 * 8];
        half8 a1 = *(half8*)&As[wm * 32 + 16 + l15][l4 * 8];
        half8 b0 = *(half8*)&Bs[wn * 32 + l15][l4 * 8];
        half8 b1 = *(half8*)&Bs[wn * 32 + 16 + l15][l4 * 8];
        acc[0][0] = __builtin_amdgcn_mfma_f32_16x16x32_f16(a0, b0, acc[0][0], 0, 0, 0);
        acc[0][1] = __builtin_amdgcn_mfma_f32_16x16x32_f16(a0, b1, acc[0][1], 0, 0, 0);
        acc[1][0] = __builtin_amdgcn_mfma_f32_16x16x32_f16(a1, b0, acc[1][0], 0, 0, 0);
        acc[1][1] = __builtin_amdgcn_mfma_f32_16x16x32_f16(a1, b1, acc[1][1], 0, 0, 0);
        __syncthreads();
    }

    // C/D layout: col = lane&15, row = (lane>>4)*4 + j   (m89-verified)
    const int colb = bn * 64 + wn * 32 + l15;
    const int rowb = bm * 64 + wm * 32 + l4 * 4;
    #pragma unroll
    for (int fm = 0; fm < 2; ++fm)
        #pragma unroll
        for (int fn = 0; fn < 2; ++fn) {
            const int cg = colb + fn * 16;
            const int rg = rowb + fm * 16;
            if (mode == 0) {
                float* Cp = Cf + (size_t)bz * M * N;
                #pragma unroll
                for (int j = 0; j < 4; ++j)
                    Cp[(size_t)(rg + j) * N + cg] = acc[fm][fn][j];
            } else {
                const float bv = bias ? bias[cg] : 0.f;
                #pragma unroll
                for (int j = 0; j < 4; ++j) {
                    float v = acc[fm][fn][j] + bv;
                    if (mode == 1)      Cf[(size_t)(rg + j) * N + cg] = v;
                    else if (mode == 2) Ch[(size_t)(rg + j) * N + cg] = (_Float16)fmaxf(v, 0.f);
                    else                Ch[(size_t)(rg + j) * N + cg] = (_Float16)v;
                }
            }
        }
}

// ---------------------------------------------------------------------------
// LSTM pointwise: z = slab0 + slab1 + bias (slabs 128x4096 fp32), gates,
// c (fp32, in-place), h out as fp16.  Layer-1 also writes the hs ring slot.
// ---------------------------------------------------------------------------
__global__ __launch_bounds__(256)
void lstm_pw(const float* __restrict__ zp, const float* __restrict__ bias,
             float* __restrict__ c, _Float16* __restrict__ hH,
             _Float16* __restrict__ hsslot, const _Float16* __restrict__ hotherH)
{
    int idx = blockIdx.x * 256 + threadIdx.x;   // < 131072
    int b = idx >> 10, j = idx & 1023;
    const float* p0 = zp + (size_t)b * 4096;
    const float* p1 = p0 + 524288;              // slab stride = 128*4096
    float zf = bias[j]        + p0[j]        + p1[j];
    float zi = bias[1024 + j] + p0[1024 + j] + p1[1024 + j];
    float zo = bias[2048 + j] + p0[2048 + j] + p1[2048 + j];
    float zm = bias[3072 + j] + p0[3072 + j] + p1[3072 + j];
    float f = sigmoidf_(zf), ii = sigmoidf_(zi), o = sigmoidf_(zo);
    float m = tanhf(zm);
    float cn = c[idx] * f + m * ii;
    float hn = tanhf(cn) * o;
    c[idx] = cn;
    hH[idx] = (_Float16)hn;
    if (hsslot) {
        hsslot[b * 2048 + 1024 + j] = (_Float16)hn;
        hsslot[b * 2048 + j] = hotherH[idx];
    }
}

// ---------------------------------------------------------------------------
// Attention over the 32-slot hs ring: slot s holds step tw where tw&31 == s.
// Window tw = t-31..t; tw<0 rows have score 0 (matches reference's zero rows)
// and contribute nothing to the weighted sum.
// ---------------------------------------------------------------------------
__global__ __launch_bounds__(256)
void attn_h(const _Float16* __restrict__ ring, int t, _Float16* __restrict__ faH)
{
    const int b = blockIdx.x;
    const int tid = threadIdx.x;
    __shared__ float hsl[2048];
    __shared__ float pl[32];

    const _Float16* hs = ring + ((size_t)(t & 31) * B_ + b) * 2048;
    for (int i = tid; i < 2048; i += 256) hsl[i] = (float)hs[i];
    __syncthreads();

    const int wv = tid >> 6, lane = tid & 63;
    for (int w = wv; w < 32; w += 4) {
        int tw = t - 31 + w;
        float s = 0.f;
        if (tw >= 0) {
            const _Float16* br = ring + ((size_t)(tw & 31) * B_ + b) * 2048;
            for (int hh = lane; hh < 2048; hh += 64) s += (float)br[hh] * hsl[hh];
        }
        #pragma unroll
        for (int off = 32; off > 0; off >>= 1) s += __shfl_down(s, off);
        if (lane == 0) pl[w] = s;
    }
    __syncthreads();

    if (tid < 64) {
        float v = (lane < 32) ? pl[lane] : -3.4e38f;
        float m = v;
        #pragma unroll
        for (int off = 32; off > 0; off >>= 1) m = fmaxf(m, __shfl_xor(m, off));
        float e = (lane < 32) ? expf(v - m) : 0.f;
        float ssum = e;
        #pragma unroll
        for (int off = 32; off > 0; off >>= 1) ssum += __shfl_xor(ssum, off);
        if (lane < 32) pl[lane] = e / ssum;
    }
    __syncthreads();

    for (int hh = tid; hh < 2048; hh += 256) {
        float a = 0.f;
        #pragma unroll
        for (int w = 0; w < 32; ++w) {
            int tw = t - 31 + w;
            if (tw >= 0)
                a += pl[w] * (float)ring[((size_t)(tw & 31) * B_ + b) * 2048 + hh];
        }
        faH[b * 2048 + hh] = (_Float16)a;
    }
}

// gatedH = (f16)(sigmoid(G) * hs)
__global__ __launch_bounds__(256)
void gate_epi(const _Float16* __restrict__ Gh, const _Float16* __restrict__ hsC,
              _Float16* __restrict__ gatedH)
{
    int idx = blockIdx.x * 256 + threadIdx.x;   // < 4096*2048
    gatedH[idx] = (_Float16)(sigmoidf_((float)Gh[idx]) * (float)hsC[idx]);
}

// WT[n][k] = (f16)W[k][n], zero-padded to Kp rows of k
__global__ __launch_bounds__(256)
void transpose_cast(const float* __restrict__ W, int K, int N,
                    _Float16* __restrict__ WT, int Kp)
{
    __shared__ float tile[32][33];
    const int tx = threadIdx.x & 31, ty8 = threadIdx.x >> 5;
    const int k0 = blockIdx.y * 32, n0 = blockIdx.x * 32;
    for (int yy = ty8; yy < 32; yy += 8) {
        int k = k0 + yy;
        tile[yy][tx] = (k < K) ? W[(size_t)k * N + n0 + tx] : 0.f;
    }
    __syncthreads();
    for (int yy = ty8; yy < 32; yy += 8)
        WT[(size_t)(n0 + yy) * Kp + k0 + tx] = (_Float16)tile[tx][yy];
}

// inpHc[r][0..287] = (f16)inp_chunk[r][0..257], zero-padded (4096 rows)
__global__ __launch_bounds__(256)
void cast_pad_inp(const float* __restrict__ inp, _Float16* __restrict__ inpH)
{
    int idx = blockIdx.x * 256 + threadIdx.x;   // < 4096*288
    int r = idx / 288, k = idx - r * 288;
    inpH[idx] = (k < 258) ? (_Float16)inp[(size_t)r * 258 + k] : (_Float16)0.f;
}

// ---------------------------------------------------------------------------
extern "C" void kernel_launch(void* const* d_in, const int* in_sizes, int n_in,
                              void* d_out, int out_size, void* d_ws, size_t ws_size,
                              hipStream_t stream)
{
    const float* inp  = (const float*)d_in[0];
    const float* embW = (const float*)d_in[1];
    const float* embB = (const float*)d_in[2];
    const float* M0   = (const float*)d_in[3];
    const float* B0   = (const float*)d_in[4];
    const float* M1   = (const float*)d_in[5];
    const float* B1   = (const float*)d_in[6];
    const float* Wg   = (const float*)d_in[7];
    const float* We   = (const float*)d_in[8];
    const float* be   = (const float*)d_in[9];
    const float* Wo   = (const float*)d_in[10];
    const float* bo   = (const float*)d_in[11];
    float* out = (float*)d_out;

    // ---- workspace layout (bytes), total ~135.3 MB (< proven-good 143 MB) ----
    char* p = (char*)d_ws;
    float*    c0    = (float*)p;      p += 524288;
    float*    c1    = (float*)p;      p += 524288;
    _Float16* h0H   = (_Float16*)p;   p += 262144;
    _Float16* h1H   = (_Float16*)p;   p += 262144;
    _Float16* faH   = (_Float16*)p;   p += 524288;
    char* zero_base = (char*)c0; size_t zero_bytes = (size_t)(p - zero_base);
    _Float16* inpHc = (_Float16*)p;   p += (size_t)4096 * 288 * 2;    // 32-step chunk
    _Float16* embWT = (_Float16*)p;   p += (size_t)512 * 288 * 2;
    _Float16* M0T   = (_Float16*)p;   p += (size_t)4096 * 3584 * 2;
    _Float16* M1T   = (_Float16*)p;   p += (size_t)4096 * 2048 * 2;
    _Float16* WgT   = (_Float16*)p;   p += (size_t)2048 * 2048 * 2;
    _Float16* WeT   = (_Float16*)p;   p += (size_t)1024 * 2048 * 2;
    _Float16* WoT   = (_Float16*)p;   p += (size_t)256 * 1024 * 2;
    _Float16* Ec    = (_Float16*)p;   p += (size_t)4096 * 512 * 2;    // 32-step chunk
    _Float16* ring  = (_Float16*)p;   p += (size_t)32 * B_ * H_ * 2;  // hs ring
    float*    z0p   = (float*)p;      p += (size_t)2 * 524288 * 4;
    float*    z1p   = (float*)p;      p += (size_t)2 * 524288 * 4;
    _Float16* Gh    = (_Float16*)p;   p += (size_t)4096 * 2048 * 2;
    _Float16* gatedH= (_Float16*)p;   p += (size_t)4096 * 2048 * 2;
    _Float16* RH    = (_Float16*)p;   p += (size_t)4096 * 1024 * 2;
    if ((size_t)(p - (char*)d_ws) > ws_size) return;   // ws too small — bail

    hipMemsetAsync(zero_base, 0, zero_bytes, stream);

    // one-time weight prep
    transpose_cast<<<dim3(16, 9),   256, 0, stream>>>(embW, 258, 512, embWT, 288);
    transpose_cast<<<dim3(128, 112),256, 0, stream>>>(M0, 3584, 4096, M0T, 3584);
    transpose_cast<<<dim3(128, 64), 256, 0, stream>>>(M1, 2048, 4096, M1T, 2048);
    transpose_cast<<<dim3(64, 64),  256, 0, stream>>>(Wg, 2048, 2048, WgT, 2048);
    transpose_cast<<<dim3(32, 64),  256, 0, stream>>>(We, 2048, 1024, WeT, 2048);
    transpose_cast<<<dim3(8, 32),   256, 0, stream>>>(Wo, 1024, 256,  WoT, 1024);

    for (int t = 0; t < T_; ++t) {
        // chunk prologue: embed 32 steps ahead of use
        if ((t & 31) == 0) {
            cast_pad_inp<<<4608, 256, 0, stream>>>(inp + (size_t)t * B_ * 258, inpHc);
            gemm_h<<<dim3(8, 64, 1), 256, 0, stream>>>(
                inpHc, 288, 288, nullptr, 0, 0, nullptr, 0, 0,
                embWT, 288, 512, 288, 288, 4096, nullptr, Ec, embB, 3);
        }
        const _Float16* Et = Ec + (size_t)(t & 31) * B_ * EMB_;
        _Float16* hsslot = ring + (size_t)(t & 31) * B_ * H_;

        // z0 = [E_t, fa, h0] @ M0   K=3584, split-K=2
        gemm_h<<<dim3(64, 2, 2), 256, 0, stream>>>(
            Et, 512, 512, faH, 2048, 2048, h0H, 1024, 1024,
            M0T, 3584, 4096, 3584, 1792, 128, z0p, nullptr, nullptr, 0);
        lstm_pw<<<512, 256, 0, stream>>>(z0p, B0, c0, h0H, nullptr, nullptr);

        // z1 = [h0, h1] @ M1   K=2048, split-K=2
        gemm_h<<<dim3(64, 2, 2), 256, 0, stream>>>(
            h0H, 1024, 1024, h1H, 1024, 1024, nullptr, 0, 0,
            M1T, 2048, 4096, 2048, 1024, 128, z1p, nullptr, nullptr, 0);
        lstm_pw<<<512, 256, 0, stream>>>(z1p, B1, c1, h1H, hsslot, h0H);

        attn_h<<<128, 256, 0, stream>>>(ring, t, faH);

        // chunk epilogue: batched head over steps t-31..t (ring slots 0..31)
        if ((t & 31) == 31) {
            const int cch = t >> 5;
            gemm_h<<<dim3(32, 64, 1), 256, 0, stream>>>(
                ring, 2048, 2048, nullptr, 0, 0, nullptr, 0, 0,
                WgT, 2048, 2048, 2048, 2048, 4096, nullptr, Gh, nullptr, 3);
            gate_epi<<<32768, 256, 0, stream>>>(Gh, ring, gatedH);
            gemm_h<<<dim3(16, 64, 1), 256, 0, stream>>>(
                gatedH, 2048, 2048, nullptr, 0, 0, nullptr, 0, 0,
                WeT, 2048, 1024, 2048, 2048, 4096, nullptr, RH, be, 2);
            gemm_h<<<dim3(4, 64, 1), 256, 0, stream>>>(
                RH, 1024, 1024, nullptr, 0, 0, nullptr, 0, 0,
                WoT, 1024, 256, 1024, 1024, 4096,
                out + (size_t)cch * 32 * B_ * VOC_, nullptr, bo, 1);
        }
    }
}

// Round 4
// 31893.375 us; speedup vs baseline: 3.2418x; 1.2709x over previous
//
#include <hip/hip_runtime.h>
#include <hip/hip_bf16.h>
#include <math.h>

#define T_ 256
#define B_ 128
#define VOC_ 256
#define EMB_ 512
#define N_ 1024
#define H_ 2048
#define WIN_ 32
#define OUT_EMB_ 1024

typedef _Float16 half8 __attribute__((ext_vector_type(8)));
typedef float f32x4 __attribute__((ext_vector_type(4)));

__device__ __forceinline__ float sigmoidf_(float x) { return 1.f / (1.f + expf(-x)); }

// ---------------------------------------------------------------------------
// Fused LSTM GEMM + gate epilogue.
// z = concat_K(A0,A1,A2) @ WT^T  where WT is gate-interleaved: WT row (4j+g)
// = original output column g*1024+j, k-contiguous.  Tile 64x32, 4 waves
// (2x2 of 32x16), BK=64, 2-deep register prefetch + double-buffered LDS.
// Epilogue: adjacent lanes hold (f,i,o,m) for quad j -> shfl_xor exchange,
// owner lane (col%4==0) computes gates, RMWs c (fp32), writes h (fp16) and
// the attention ring slot.  Requires Ktot%128==0 (even NIT), segments %64.
// ---------------------------------------------------------------------------
__global__ __launch_bounds__(256)
void lstm_gemm(const _Float16* __restrict__ A0, int k0, int lda0,
               const _Float16* __restrict__ A1, int k1, int lda1,
               const _Float16* __restrict__ A2, int k2, int lda2,
               const _Float16* __restrict__ WT, int Ktot,
               const float* __restrict__ bias,
               float* __restrict__ c, _Float16* __restrict__ hH,
               _Float16* __restrict__ ringSlot, int ringHalf)
{
    __shared__ _Float16 As[2][64][72];   // 72 = 64 + 8 pad (16B-aligned rows)
    __shared__ _Float16 Bs[2][32][72];

    const int tid = threadIdx.x;
    const int bn = blockIdx.x, bm = blockIdx.y;
    const int lane = tid & 63, wid = tid >> 6;
    const int wm = wid >> 1, wn = wid & 1;
    const int l15 = lane & 15, l4 = lane >> 4;

    // staging coords: A 64x64 (2 half8/thread), B 32x64 (1 half8/thread)
    const int arow = tid >> 2, akh = (tid & 3) * 16;
    const int brow = tid >> 3, bkh = (tid & 7) * 8;
    const _Float16* Bg = WT + (size_t)(bn * 32 + brow) * Ktot;

    const int NIT = Ktot >> 6;           // even for all call sites (56, 32)

    f32x4 acc[2];
    acc[0] = (f32x4){0.f, 0.f, 0.f, 0.f};
    acc[1] = (f32x4){0.f, 0.f, 0.f, 0.f};

    half8 pa0A, pa1A, pbA, pa0B, pa1B, pbB;

    auto issue = [&](int it, half8& r0, half8& r1, half8& rb) {
        const int kb = it * 64;
        const _Float16* Ag; int so, ld;
        if (kb < k0)           { Ag = A0; so = 0;       ld = lda0; }
        else if (kb < k0 + k1) { Ag = A1; so = k0;      ld = lda1; }
        else                   { Ag = A2; so = k0 + k1; ld = lda2; }
        const _Float16* ap = Ag + (size_t)(bm * 64 + arow) * ld + (kb - so);
        r0 = *(const half8*)(ap + akh);
        r1 = *(const half8*)(ap + akh + 8);
        rb = *(const half8*)(Bg + kb + bkh);
    };
    auto wlds = [&](int buf, half8 r0, half8 r1, half8 rb) {
        *(half8*)&As[buf][arow][akh]     = r0;
        *(half8*)&As[buf][arow][akh + 8] = r1;
        *(half8*)&Bs[buf][brow][bkh]     = rb;
    };
    auto comp = [&](int buf) {
        #pragma unroll
        for (int ks = 0; ks < 2; ++ks) {
            half8 a0 = *(half8*)&As[buf][wm * 32 + l15][ks * 32 + l4 * 8];
            half8 a1 = *(half8*)&As[buf][wm * 32 + 16 + l15][ks * 32 + l4 * 8];
            half8 b0 = *(half8*)&Bs[buf][wn * 16 + l15][ks * 32 + l4 * 8];
            acc[0] = __builtin_amdgcn_mfma_f32_16x16x32_f16(a0, b0, acc[0], 0, 0, 0);
            acc[1] = __builtin_amdgcn_mfma_f32_16x16x32_f16(a1, b0, acc[1], 0, 0, 0);
        }
    };

    // prologue: tiles 0,1 in flight; tile 0 -> LDS[0]
    issue(0, pa0A, pa1A, pbA);
    issue(1, pa0B, pa1B, pbB);
    wlds(0, pa0A, pa1A, pbA);
    __syncthreads();

    for (int it = 0; it < NIT; it += 2) {
        // ---- iter A: compute tile it from LDS[0] ----
        comp(0);
        if (it + 2 < NIT) issue(it + 2, pa0A, pa1A, pbA);
        __syncthreads();                     // all waves done with LDS[1] (tile it-1)
        wlds(1, pa0B, pa1B, pbB);            // tile it+1 -> LDS[1] (waits its loads)
        __syncthreads();
        // ---- iter B: compute tile it+1 from LDS[1] ----
        comp(1);
        if (it + 3 < NIT) issue(it + 3, pa0B, pa1B, pbB);
        __syncthreads();                     // all waves done with LDS[0]
        if (it + 2 < NIT) wlds(0, pa0A, pa1A, pbA);
        __syncthreads();
    }

    // ---- fused LSTM epilogue ----
    // C/D layout: col = lane&15, row = (lane>>4)*4 + j
    const int cg = bn * 32 + wn * 16 + l15;      // gate-interleaved global col
    const bool owner = (cg & 3) == 0;
    const int jglob = cg >> 2;
    float bf = 0.f, bi = 0.f, bo_ = 0.f, bm_ = 0.f;
    if (owner) {
        bf  = bias[jglob];
        bi  = bias[1024 + jglob];
        bo_ = bias[2048 + jglob];
        bm_ = bias[3072 + jglob];
    }
    #pragma unroll
    for (int fm = 0; fm < 2; ++fm) {
        const int rbase = bm * 64 + wm * 32 + fm * 16 + l4 * 4;
        #pragma unroll
        for (int jr = 0; jr < 4; ++jr) {
            float v  = acc[fm][jr];
            float v1 = __shfl_xor(v, 1);     // all lanes participate
            float v2 = __shfl_xor(v, 2);
            float v3 = __shfl_xor(v, 3);
            if (owner) {
                const int r = rbase + jr;
                float zf = v + bf, zi = v1 + bi, zo = v2 + bo_, zm = v3 + bm_;
                float f = sigmoidf_(zf), ii = sigmoidf_(zi), o = sigmoidf_(zo);
                float m = tanhf(zm);
                const int ci = r * 1024 + jglob;
                float cn = c[ci] * f + m * ii;
                float hn = tanhf(cn) * o;
                c[ci] = cn;
                hH[ci] = (_Float16)hn;
                ringSlot[r * 2048 + ringHalf + jglob] = (_Float16)hn;
            }
        }
    }
}

// ---------------------------------------------------------------------------
// Plain fp16 MFMA GEMM (emb + head; occupancy-hidden latency).  Unchanged
// from the passing round-3 kernel.
// mode 1: Cf = acc + bias;  mode 2: Ch = relu;  mode 3: Ch = plain.
// ---------------------------------------------------------------------------
__global__ __launch_bounds__(256)
void gemm_h(const _Float16* __restrict__ A0, int k0, int lda0,
            const _Float16* __restrict__ BT, int ldb,
            int N, int Ktot, int M,
            float* __restrict__ Cf, _Float16* __restrict__ Ch,
            const float* __restrict__ bias, int mode)
{
    __shared__ _Float16 As[64][40];
    __shared__ _Float16 Bs[64][40];

    const int tid = threadIdx.x;
    const int bn = blockIdx.x, bm = blockIdx.y;
    const int lane = tid & 63, wid = tid >> 6;
    const int wm = wid >> 1, wn = wid & 1;
    const int l15 = lane & 15, l4 = lane >> 4;
    const int ar = tid >> 2, ak = (tid & 3) * 8;

    f32x4 acc[2][2];
    #pragma unroll
    for (int i = 0; i < 2; ++i)
        #pragma unroll
        for (int j = 0; j < 2; ++j) acc[i][j] = (f32x4){0.f, 0.f, 0.f, 0.f};

    for (int kb = 0; kb < Ktot; kb += 32) {
        *(half8*)&As[ar][ak] =
            *(const half8*)(A0 + (size_t)(bm * 64 + ar) * lda0 + (kb + ak));
        *(half8*)&Bs[ar][ak] =
            *(const half8*)(BT + (size_t)(bn * 64 + ar) * ldb + (kb + ak));
        __syncthreads();

        half8 a0 = *(half8*)&As[wm * 32 + l15][l4 * 8];
        half8 a1 = *(half8*)&As[wm * 32 + 16 + l15][l4 * 8];
        half8 b0 = *(half8*)&Bs[wn * 32 + l15][l4 * 8];
        half8 b1 = *(half8*)&Bs[wn * 32 + 16 + l15][l4 * 8];
        acc[0][0] = __builtin_amdgcn_mfma_f32_16x16x32_f16(a0, b0, acc[0][0], 0, 0, 0);
        acc[0][1] = __builtin_amdgcn_mfma_f32_16x16x32_f16(a0, b1, acc[0][1], 0, 0, 0);
        acc[1][0] = __builtin_amdgcn_mfma_f32_16x16x32_f16(a1, b0, acc[1][0], 0, 0, 0);
        acc[1][1] = __builtin_amdgcn_mfma_f32_16x16x32_f16(a1, b1, acc[1][1], 0, 0, 0);
        __syncthreads();
    }

    const int colb = bn * 64 + wn * 32 + l15;
    const int rowb = bm * 64 + wm * 32 + l4 * 4;
    #pragma unroll
    for (int fm = 0; fm < 2; ++fm)
        #pragma unroll
        for (int fn = 0; fn < 2; ++fn) {
            const int cgc = colb + fn * 16;
            const int rg = rowb + fm * 16;
            const float bv = bias ? bias[cgc] : 0.f;
            #pragma unroll
            for (int j = 0; j < 4; ++j) {
                float v = acc[fm][fn][j] + bv;
                if (mode == 1)      Cf[(size_t)(rg + j) * N + cgc] = v;
                else if (mode == 2) Ch[(size_t)(rg + j) * N + cgc] = (_Float16)fmaxf(v, 0.f);
                else                Ch[(size_t)(rg + j) * N + cgc] = (_Float16)v;
            }
        }
}

// ---------------------------------------------------------------------------
// Attention over the 32-slot hs ring (vectorized half8 loads).
// ---------------------------------------------------------------------------
__global__ __launch_bounds__(256)
void attn_h(const _Float16* __restrict__ ring, int t, _Float16* __restrict__ faH)
{
    const int b = blockIdx.x, tid = threadIdx.x;
    __shared__ float hsl[2048];
    __shared__ float pl[32];

    const _Float16* hs = ring + ((size_t)(t & 31) * B_ + b) * 2048;
    {
        half8 v = *(const half8*)(hs + tid * 8);
        #pragma unroll
        for (int e = 0; e < 8; ++e) hsl[tid * 8 + e] = (float)v[e];
    }
    __syncthreads();

    const int wv = tid >> 6, lane = tid & 63;
    #pragma unroll
    for (int w8 = 0; w8 < 8; ++w8) {
        const int w = wv * 8 + w8;
        const int tw = t - 31 + w;
        float s = 0.f;
        if (tw >= 0) {
            const _Float16* br = ring + ((size_t)(tw & 31) * B_ + b) * 2048;
            #pragma unroll
            for (int p2 = 0; p2 < 4; ++p2) {
                half8 v = *(const half8*)(br + p2 * 512 + lane * 8);
                const float* hp = &hsl[p2 * 512 + lane * 8];
                #pragma unroll
                for (int e = 0; e < 8; ++e) s += (float)v[e] * hp[e];
            }
        }
        #pragma unroll
        for (int off = 32; off > 0; off >>= 1) s += __shfl_xor(s, off);
        if (lane == 0) pl[w] = s;
    }
    __syncthreads();

    if (tid < 64) {
        float v = (lane < 32) ? pl[lane] : -3.4e38f;
        float m = v;
        #pragma unroll
        for (int off = 32; off > 0; off >>= 1) m = fmaxf(m, __shfl_xor(m, off));
        float e = (lane < 32) ? expf(v - m) : 0.f;
        float ssum = e;
        #pragma unroll
        for (int off = 32; off > 0; off >>= 1) ssum += __shfl_xor(ssum, off);
        if (lane < 32) pl[lane] = e / ssum;
    }
    __syncthreads();

    // weighted sum: thread owns 8 h-dims
    float a[8] = {0.f, 0.f, 0.f, 0.f, 0.f, 0.f, 0.f, 0.f};
    for (int w = 0; w < 32; ++w) {
        const int tw = t - 31 + w;
        if (tw >= 0) {
            const float pw = pl[w];
            half8 v = *(const half8*)(ring + ((size_t)(tw & 31) * B_ + b) * 2048 + tid * 8);
            #pragma unroll
            for (int e = 0; e < 8; ++e) a[e] += pw * (float)v[e];
        }
    }
    #pragma unroll
    for (int e = 0; e < 8; ++e) faH[b * 2048 + tid * 8 + e] = (_Float16)a[e];
}

// gatedH = (f16)(sigmoid(G) * hs)
__global__ __launch_bounds__(256)
void gate_epi(const _Float16* __restrict__ Gh, const _Float16* __restrict__ hsC,
              _Float16* __restrict__ gatedH)
{
    int idx = blockIdx.x * 256 + threadIdx.x;
    gatedH[idx] = (_Float16)(sigmoidf_((float)Gh[idx]) * (float)hsC[idx]);
}

// WT[n'][k] = (f16)W[k][n], zero-padded to Kp; gperm: n' = ((n&1023)<<2)|(n>>10)
__global__ __launch_bounds__(256)
void transpose_cast(const float* __restrict__ W, int K, int N,
                    _Float16* __restrict__ WT, int Kp, int gperm)
{
    __shared__ float tile[32][33];
    const int tx = threadIdx.x & 31, ty8 = threadIdx.x >> 5;
    const int k0 = blockIdx.y * 32, n0 = blockIdx.x * 32;
    for (int yy = ty8; yy < 32; yy += 8) {
        int k = k0 + yy;
        tile[yy][tx] = (k < K) ? W[(size_t)k * N + n0 + tx] : 0.f;
    }
    __syncthreads();
    for (int yy = ty8; yy < 32; yy += 8) {
        int n = n0 + yy;
        int nd = gperm ? (((n & 1023) << 2) | (n >> 10)) : n;
        WT[(size_t)nd * Kp + k0 + tx] = (_Float16)tile[tx][yy];
    }
}

// inpHc[r][0..287] = (f16)inp_chunk[r][0..257], zero-padded (4096 rows)
__global__ __launch_bounds__(256)
void cast_pad_inp(const float* __restrict__ inp, _Float16* __restrict__ inpH)
{
    int idx = blockIdx.x * 256 + threadIdx.x;
    int r = idx / 288, k = idx - r * 288;
    inpH[idx] = (k < 258) ? (_Float16)inp[(size_t)r * 258 + k] : (_Float16)0.f;
}

// ---------------------------------------------------------------------------
extern "C" void kernel_launch(void* const* d_in, const int* in_sizes, int n_in,
                              void* d_out, int out_size, void* d_ws, size_t ws_size,
                              hipStream_t stream)
{
    const float* inp  = (const float*)d_in[0];
    const float* embW = (const float*)d_in[1];
    const float* embB = (const float*)d_in[2];
    const float* M0   = (const float*)d_in[3];
    const float* B0   = (const float*)d_in[4];
    const float* M1   = (const float*)d_in[5];
    const float* B1   = (const float*)d_in[6];
    const float* Wg   = (const float*)d_in[7];
    const float* We   = (const float*)d_in[8];
    const float* be   = (const float*)d_in[9];
    const float* Wo   = (const float*)d_in[10];
    const float* bo   = (const float*)d_in[11];
    float* out = (float*)d_out;

    // ---- workspace (bytes), total ~127.4 MB ----
    char* p = (char*)d_ws;
    float*    c0    = (float*)p;      p += 524288;
    float*    c1    = (float*)p;      p += 524288;
    _Float16* h0H   = (_Float16*)p;   p += 524288;   // 2 parity buffers
    _Float16* h1H   = (_Float16*)p;   p += 524288;   // 2 parity buffers
    _Float16* faH   = (_Float16*)p;   p += 524288;
    char* zero_base = (char*)c0; size_t zero_bytes = (size_t)(p - zero_base);
    _Float16* inpHc = (_Float16*)p;   p += (size_t)4096 * 288 * 2;
    _Float16* embWT = (_Float16*)p;   p += (size_t)512 * 288 * 2;
    _Float16* M0T   = (_Float16*)p;   p += (size_t)4096 * 3584 * 2;
    _Float16* M1T   = (_Float16*)p;   p += (size_t)4096 * 2048 * 2;
    _Float16* WgT   = (_Float16*)p;   p += (size_t)2048 * 2048 * 2;
    _Float16* WeT   = (_Float16*)p;   p += (size_t)1024 * 2048 * 2;
    _Float16* WoT   = (_Float16*)p;   p += (size_t)256 * 1024 * 2;
    _Float16* Ec    = (_Float16*)p;   p += (size_t)4096 * 512 * 2;
    _Float16* ring  = (_Float16*)p;   p += (size_t)32 * B_ * H_ * 2;
    _Float16* Gh    = (_Float16*)p;   p += (size_t)4096 * 2048 * 2;
    _Float16* gatedH= (_Float16*)p;   p += (size_t)4096 * 2048 * 2;
    _Float16* RH    = (_Float16*)p;   p += (size_t)4096 * 1024 * 2;
    if ((size_t)(p - (char*)d_ws) > ws_size) return;

    hipMemsetAsync(zero_base, 0, zero_bytes, stream);

    // one-time weight prep (M0/M1 gate-interleaved)
    transpose_cast<<<dim3(16, 9),   256, 0, stream>>>(embW, 258, 512, embWT, 288, 0);
    transpose_cast<<<dim3(128, 112),256, 0, stream>>>(M0, 3584, 4096, M0T, 3584, 1);
    transpose_cast<<<dim3(128, 64), 256, 0, stream>>>(M1, 2048, 4096, M1T, 2048, 1);
    transpose_cast<<<dim3(64, 64),  256, 0, stream>>>(Wg, 2048, 2048, WgT, 2048, 0);
    transpose_cast<<<dim3(32, 64),  256, 0, stream>>>(We, 2048, 1024, WeT, 2048, 0);
    transpose_cast<<<dim3(8, 32),   256, 0, stream>>>(Wo, 1024, 256,  WoT, 1024, 0);

    for (int t = 0; t < T_; ++t) {
        if ((t & 31) == 0) {
            cast_pad_inp<<<4608, 256, 0, stream>>>(inp + (size_t)t * B_ * 258, inpHc);
            gemm_h<<<dim3(8, 64), 256, 0, stream>>>(
                inpHc, 288, 288, embWT, 288, 512, 288, 4096, nullptr, Ec, embB, 3);
        }
        const _Float16* Et = Ec + (size_t)(t & 31) * B_ * EMB_;
        _Float16* ringSlot = ring + (size_t)(t & 31) * B_ * H_;
        _Float16* h0p = h0H + (size_t)(t & 1) * 131072;
        _Float16* h0c = h0H + (size_t)((t + 1) & 1) * 131072;
        _Float16* h1p = h1H + (size_t)(t & 1) * 131072;
        _Float16* h1c = h1H + (size_t)((t + 1) & 1) * 131072;

        // z0 = [E_t, fa, h0] @ M0 (K=3584), fused LSTM0
        lstm_gemm<<<dim3(128, 2), 256, 0, stream>>>(
            Et, 512, 512, faH, 2048, 2048, h0p, 1024, 1024,
            M0T, 3584, B0, c0, h0c, ringSlot, 0);

        // z1 = [h0, h1] @ M1 (K=2048), fused LSTM1
        lstm_gemm<<<dim3(128, 2), 256, 0, stream>>>(
            h0c, 1024, 1024, h1p, 1024, 1024, nullptr, 0, 0,
            M1T, 2048, B1, c1, h1c, ringSlot, 1024);

        attn_h<<<128, 256, 0, stream>>>(ring, t, faH);

        if ((t & 31) == 31) {
            const int cch = t >> 5;
            gemm_h<<<dim3(32, 64), 256, 0, stream>>>(
                ring, 2048, 2048, WgT, 2048, 2048, 2048, 4096, nullptr, Gh, nullptr, 3);
            gate_epi<<<32768, 256, 0, stream>>>(Gh, ring, gatedH);
            gemm_h<<<dim3(16, 64), 256, 0, stream>>>(
                gatedH, 2048, 2048, WeT, 2048, 1024, 2048, 4096, nullptr, RH, be, 2);
            gemm_h<<<dim3(4, 64), 256, 0, stream>>>(
                RH, 1024, 1024, WoT, 1024, 256, 1024, 4096,
                out + (size_t)cch * 32 * B_ * VOC_, nullptr, bo, 1);
        }
    }
}